// Round 18
// baseline (332.054 us; speedup 1.0000x reference)
//
#include <hip/hip_runtime.h>

#define E_EDGES 320000
#define NN 20000
#define HID 128
#define TS 136   // LDS T-tile stride (bf16 elems): 272B == 16 mod 128 -> spread banks

typedef __attribute__((ext_vector_type(8))) short short8;
typedef __attribute__((ext_vector_type(4))) float f32x4;
typedef __attribute__((ext_vector_type(8))) unsigned short us8;
typedef __attribute__((ext_vector_type(4))) unsigned uint4v;

__device__ __forceinline__ unsigned short f2b(float f) {
  unsigned u = __builtin_bit_cast(unsigned, f);
  u += 0x7fffu + ((u >> 16) & 1u);
  return (unsigned short)(u >> 16);
}
__device__ __forceinline__ unsigned cvt_pk_bf16(float lo, float hi) {
  unsigned r;
  asm("v_cvt_pk_bf16_f32 %0, %1, %2" : "=v"(r) : "v"(lo), "v"(hi));
  return r;
}
#define LOG2E 1.44269504f
__device__ __forceinline__ float fast_sigmoid(float x) {
  return __builtin_amdgcn_rcpf(1.0f + __builtin_amdgcn_exp2f(-x * LOG2E));
}
__device__ __forceinline__ float silu_f(float x) { return x * fast_sigmoid(x); }

// ---------------- K1: weight prepack + zero nf (stride-12) -------------------
__global__ void prepack_k(const float* __restrict__ Wce1, const float* __restrict__ Wce2,
                          const float* __restrict__ Ws1,  const float* __restrict__ Ws2,
                          const float* __restrict__ Wpe2, const float* __restrict__ Wpe1,
                          unsigned short* __restrict__ dst, float* __restrict__ nf) {
  int b = blockIdx.x;
  if (b >= 400) {
    int j = (b - 400) * 256 + threadIdx.x;
    if (j < NN * 12 / 4)
      reinterpret_cast<float4*>(nf)[j] = float4{0.0f, 0.0f, 0.0f, 0.0f};
    return;
  }
  int i = b * 256 + threadIdx.x;
  const float* W; int Ksrc, base;
  if (i < 32768)      { W = Wce1; Ksrc = 256; base = 0; }
  else if (i < 49152) { W = Wce2; Ksrc = 128; base = 32768; }
  else if (i < 65536) { W = Ws1;  Ksrc = 128; base = 49152; }
  else if (i < 81920) { W = Ws2;  Ksrc = 128; base = 65536; }
  else if (i < 98304) { W = Wpe2; Ksrc = 128; base = 81920; }
  else                { W = Wpe1; Ksrc = 18;  base = 98304; }
  int j = i - base;
  int r = j & 7, lane = (j >> 3) & 63, ntg = (j >> 9) & 7, kt = j >> 12;
  int sk = kt * 32 + ((lane >> 4) << 3) + r;
  int sn = (ntg << 4) + (lane & 15);
  float v = (sk < Ksrc) ? W[sk * HID + sn] : 0.0f;
  dst[i] = f2b(v);
}

// ---------------- K2: edge geometry (blocks 0..1249) + node ce1 (1250..1874) --
__global__ __launch_bounds__(256) void geomnode_k(
    const int* __restrict__ erow, const int* __restrict__ ecol,
    const float* __restrict__ coord, const float* __restrict__ h,
    const unsigned short* __restrict__ wp, const float* __restrict__ b1,
    float* __restrict__ nf, unsigned short* __restrict__ rad16,
    float* __restrict__ cdn,
    unsigned short* __restrict__ Htb, unsigned short* __restrict__ Hbb) {
  int b = blockIdx.x;
  if (b < 1250) {
    int i = b * 256 + threadIdx.x;
    int r = erow[i], c = ecol[i];
    float dx = coord[r*3+0] - coord[c*3+0];
    float dy = coord[r*3+1] - coord[c*3+1];
    float dz = coord[r*3+2] - coord[c*3+2];
    float r2 = dx*dx + dy*dy + dz*dz;
    float dn = sqrtf(r2);
    float invn = __builtin_amdgcn_rcpf(dn + 1e-8f);
    cdn[i*3+0] = dx*invn; cdn[i*3+1] = dy*invn; cdn[i*3+2] = dz*invn;

    unsigned short rv[16];
    float t = 1.0f;
    #pragma unroll
    for (int s = 0; s < 15; s++) {
      rv[s] = f2b(__builtin_amdgcn_exp2f(r2 * (-0.5f * LOG2E) / t));
      t *= 2.25f;
    }
    rv[15] = 0;
    us8 lo, hi;
    #pragma unroll
    for (int k = 0; k < 8; k++) { lo[k] = rv[k]; hi[k] = rv[8+k]; }
    *reinterpret_cast<us8*>(rad16 + (size_t)i*16)     = lo;
    *reinterpret_cast<us8*>(rad16 + (size_t)i*16 + 8) = hi;

    float inv = __builtin_amdgcn_rcpf(dn);
    float w3 = inv*inv*inv, w4 = w3*inv, w5 = w4*inv;
    float* p = nf + r*12;
    unsafeAtomicAdd(p+0, w3*dx); unsafeAtomicAdd(p+1, w3*dy); unsafeAtomicAdd(p+2, w3*dz);
    unsafeAtomicAdd(p+3, w4*dx); unsafeAtomicAdd(p+4, w4*dy); unsafeAtomicAdd(p+5, w4*dz);
    unsafeAtomicAdd(p+6, w5*dx); unsafeAtomicAdd(p+7, w5*dy); unsafeAtomicAdd(p+8, w5*dz);
    return;
  }
  const int tid = threadIdx.x, lane = tid & 63, wv = tid >> 6;
  const int cl = lane & 15, kg = lane >> 4;
  const int w = (b - 1250) * 4 + wv;   // 0..2499
  const int half = w & 1;
  const int n0 = (w >> 1) * 16;

  f32x4 acc[8];
  #pragma unroll
  for (int nt = 0; nt < 8; nt++) {
    float bb = half ? 0.0f : b1[nt*16 + cl];
    acc[nt] = f32x4{bb, bb, bb, bb};
  }
  #pragma unroll
  for (int k4 = 0; k4 < 4; k4++) {
    int kt = half*4 + k4;
    const float* hp = h + (size_t)(n0 + cl) * HID + k4*32 + kg*8;
    float4 v0 = *reinterpret_cast<const float4*>(hp);
    float4 v1 = *reinterpret_cast<const float4*>(hp + 4);
    unsigned p0 = cvt_pk_bf16(v0.x, v0.y), p1 = cvt_pk_bf16(v0.z, v0.w);
    unsigned p2 = cvt_pk_bf16(v1.x, v1.y), p3 = cvt_pk_bf16(v1.z, v1.w);
    short8 af = __builtin_bit_cast(short8, uint4v{p0, p1, p2, p3});
    #pragma unroll
    for (int nt = 0; nt < 8; nt++) {
      short8 bf = *reinterpret_cast<const short8*>(wp + ((kt*8 + nt)*64 + lane)*8);
      acc[nt] = __builtin_amdgcn_mfma_f32_16x16x32_bf16(af, bf, acc[nt], 0, 0, 0);
    }
  }
  unsigned short* dst = half ? Hbb : Htb;
  #pragma unroll
  for (int nt = 0; nt < 8; nt++) {
    unsigned q0 = cvt_pk_bf16(acc[nt][0], acc[nt][1]);
    unsigned q1 = cvt_pk_bf16(acc[nt][2], acc[nt][3]);
    dst[(size_t)(n0 + kg*4 + 0) * HID + nt*16 + cl] = (unsigned short)(q0 & 0xffff);
    dst[(size_t)(n0 + kg*4 + 1) * HID + nt*16 + cl] = (unsigned short)(q0 >> 16);
    dst[(size_t)(n0 + kg*4 + 2) * HID + nt*16 + cl] = (unsigned short)(q1 & 0xffff);
    dst[(size_t)(n0 + kg*4 + 3) * HID + nt*16 + cl] = (unsigned short)(q1 >> 16);
  }
}

// ---------------- K3: edge kernel v7 — 8-wave blocks, ce2+s1 weights in LDS ---
// 512 threads, 32 edges/wave. One-time stage of ce2+s1 B-matrices (64 KB) ->
// their global traffic drops 8x (per-block vs per-wave). LDS: 69.6 KB T-tiles
// + 64 KB weights = 133.6 KB, 1 block/CU, 8 waves/CU (same occupancy as R17).
// (512,2): 256-reg budget, spill-free like R17.
__global__ __launch_bounds__(512, 2) void edge_mlp_k(
    const int* __restrict__ erow, const int* __restrict__ ecol,
    const unsigned short* __restrict__ Htb, const unsigned short* __restrict__ Hbb,
    const unsigned short* __restrict__ rad16, const float* __restrict__ nf,
    const unsigned short* __restrict__ wp,
    const float* __restrict__ b2,  const float* __restrict__ bs1,
    const float* __restrict__ bs2, const float* __restrict__ bp1,
    const float* __restrict__ bp2,
    const float* __restrict__ watt, const float* __restrict__ batt,
    float* __restrict__ out0, float* __restrict__ chem_o, float* __restrict__ pos_o) {
  __shared__ unsigned short lw[32768];        // ce2 (16384) | s1 (16384)
  __shared__ unsigned short sT[8][32 * TS];
  const int tid = threadIdx.x, lane = tid & 63, wv = tid >> 6;
  const int cl = lane & 15, kg = lane >> 4;
  const int e0 = (blockIdx.x * 8 + wv) * 32;
  unsigned short* T = sT[wv];

  // one-time stage: ce2+s1 fragment blocks (wp+32768 .. wp+65536)
  #pragma unroll
  for (int it = 0; it < 8; it++) {
    int idx = (it * 512 + tid) * 8;
    *reinterpret_cast<short8*>(lw + idx) =
        *reinterpret_cast<const short8*>(wp + 32768 + idx);
  }

  int er_[2], ec_[2];
  er_[0] = erow[e0 + cl];      ec_[0] = ecol[e0 + cl];
  er_[1] = erow[e0 + 16 + cl]; ec_[1] = ecol[e0 + 16 + cl];

  // early-issue long-latency side loads (hide under ce2/s1/s2 chain)
  us8 r0[2], r1[2];
  #pragma unroll
  for (int rt = 0; rt < 2; rt++) {
    r0[rt] = *reinterpret_cast<const us8*>(rad16 + (size_t)(e0 + rt*16 + cl)*16);
    r1[rt] = *reinterpret_cast<const us8*>(rad16 + (size_t)(e0 + rt*16 + cl)*16 + 8);
  }
  float np[2][3];
  if (kg == 0) {
    #pragma unroll
    for (int rt = 0; rt < 2; rt++) {
      const float4* ap = reinterpret_cast<const float4*>(nf + er_[rt]*12);
      const float4* bp = reinterpret_cast<const float4*>(nf + ec_[rt]*12);
      float4 A0 = ap[0], A1 = ap[1], A2 = ap[2];
      float4 B0 = bp[0], B1 = bp[1], B2 = bp[2];
      {
        float d  = A0.x*B0.x + A0.y*B0.y + A0.z*B0.z;
        float na = A0.x*A0.x + A0.y*A0.y + A0.z*A0.z;
        float nb = B0.x*B0.x + B0.y*B0.y + B0.z*B0.z;
        np[rt][0] = d * __builtin_amdgcn_rcpf(sqrtf(na) + 1e-8f)
                      * __builtin_amdgcn_rcpf(sqrtf(nb) + 1e-8f);
      }
      {
        float d  = A0.w*B0.w + A1.x*B1.x + A1.y*B1.y;
        float na = A0.w*A0.w + A1.x*A1.x + A1.y*A1.y;
        float nb = B0.w*B0.w + B1.x*B1.x + B1.y*B1.y;
        np[rt][1] = d * __builtin_amdgcn_rcpf(sqrtf(na) + 1e-8f)
                      * __builtin_amdgcn_rcpf(sqrtf(nb) + 1e-8f);
      }
      {
        float d  = A1.z*B1.z + A1.w*B1.w + A2.x*B2.x;
        float na = A1.z*A1.z + A1.w*A1.w + A2.x*A2.x;
        float nb = B1.z*B1.z + B1.w*B1.w + B2.x*B2.x;
        np[rt][2] = d * __builtin_amdgcn_rcpf(sqrtf(na) + 1e-8f)
                      * __builtin_amdgcn_rcpf(sqrtf(nb) + 1e-8f);
      }
    }
  }
  __syncthreads();   // staged weights visible to all waves

  // ---- ce2: A = silu(Htop[row] + Hbot[col]) from bf16 tables; B from LDS ----
  f32x4 acc[2][8];
  #pragma unroll
  for (int nt = 0; nt < 8; nt++) {
    float bb = b2[nt*16 + cl];
    acc[0][nt] = f32x4{bb, bb, bb, bb};
    acc[1][nt] = f32x4{bb, bb, bb, bb};
  }
  #pragma unroll
  for (int kt = 0; kt < 4; kt++) {
    short8 bf[8];
    #pragma unroll
    for (int nt = 0; nt < 8; nt++)
      bf[nt] = *reinterpret_cast<const short8*>(lw + ((kt*8 + nt)*64 + lane)*8);
    #pragma unroll
    for (int rt = 0; rt < 2; rt++) {
      uint4v ta = *reinterpret_cast<const uint4v*>(Htb + (size_t)er_[rt] * HID + kt*32 + kg*8);
      uint4v tb = *reinterpret_cast<const uint4v*>(Hbb + (size_t)ec_[rt] * HID + kt*32 + kg*8);
      unsigned pw[4];
      #pragma unroll
      for (int p = 0; p < 4; p++) {
        float alo = __builtin_bit_cast(float, ta[p] << 16);
        float ahi = __builtin_bit_cast(float, ta[p] & 0xffff0000u);
        float blo = __builtin_bit_cast(float, tb[p] << 16);
        float bhi = __builtin_bit_cast(float, tb[p] & 0xffff0000u);
        pw[p] = cvt_pk_bf16(silu_f(alo + blo), silu_f(ahi + bhi));
      }
      short8 af = __builtin_bit_cast(short8, uint4v{pw[0], pw[1], pw[2], pw[3]});
      #pragma unroll
      for (int nt = 0; nt < 8; nt++)
        acc[rt][nt] = __builtin_amdgcn_mfma_f32_16x16x32_bf16(af, bf[nt], acc[rt][nt], 0, 0, 0);
    }
  }
  #pragma unroll
  for (int rt = 0; rt < 2; rt++)
    #pragma unroll
    for (int nt = 0; nt < 8; nt++) {
      #pragma unroll
      for (int g = 0; g < 4; g++)
        chem_o[(size_t)(e0 + rt*16 + kg*4 + g) * HID + nt*16 + cl] = acc[rt][nt][g];
      unsigned q0 = cvt_pk_bf16(acc[rt][nt][0], acc[rt][nt][1]);
      unsigned q1 = cvt_pk_bf16(acc[rt][nt][2], acc[rt][nt][3]);
      T[(rt*16 + kg*4 + 0)*TS + nt*16 + cl] = (unsigned short)(q0 & 0xffff);
      T[(rt*16 + kg*4 + 1)*TS + nt*16 + cl] = (unsigned short)(q0 >> 16);
      T[(rt*16 + kg*4 + 2)*TS + nt*16 + cl] = (unsigned short)(q1 & 0xffff);
      T[(rt*16 + kg*4 + 3)*TS + nt*16 + cl] = (unsigned short)(q1 >> 16);
    }

  // ---- s1: silu(T @ Ws1 + bs1) -> T (B from LDS at lw+16384) ----
  #pragma unroll
  for (int nt = 0; nt < 8; nt++) {
    float bb = bs1[nt*16 + cl];
    acc[0][nt] = f32x4{bb, bb, bb, bb};
    acc[1][nt] = f32x4{bb, bb, bb, bb};
  }
  #pragma unroll
  for (int kt = 0; kt < 4; kt++) {
    short8 bf[8];
    #pragma unroll
    for (int nt = 0; nt < 8; nt++)
      bf[nt] = *reinterpret_cast<const short8*>(lw + 16384 + ((kt*8 + nt)*64 + lane)*8);
    #pragma unroll
    for (int rt = 0; rt < 2; rt++) {
      short8 af = *reinterpret_cast<const short8*>(T + (rt*16 + cl)*TS + kt*32 + kg*8);
      #pragma unroll
      for (int nt = 0; nt < 8; nt++)
        acc[rt][nt] = __builtin_amdgcn_mfma_f32_16x16x32_bf16(af, bf[nt], acc[rt][nt], 0, 0, 0);
    }
  }
  #pragma unroll
  for (int rt = 0; rt < 2; rt++)
    #pragma unroll
    for (int nt = 0; nt < 8; nt++) {
      unsigned q0 = cvt_pk_bf16(silu_f(acc[rt][nt][0]), silu_f(acc[rt][nt][1]));
      unsigned q1 = cvt_pk_bf16(silu_f(acc[rt][nt][2]), silu_f(acc[rt][nt][3]));
      T[(rt*16 + kg*4 + 0)*TS + nt*16 + cl] = (unsigned short)(q0 & 0xffff);
      T[(rt*16 + kg*4 + 1)*TS + nt*16 + cl] = (unsigned short)(q0 >> 16);
      T[(rt*16 + kg*4 + 2)*TS + nt*16 + cl] = (unsigned short)(q1 & 0xffff);
      T[(rt*16 + kg*4 + 3)*TS + nt*16 + cl] = (unsigned short)(q1 >> 16);
    }

  // ---- s2 -> accS (held; B from global, L1-hot) ----
  f32x4 accS[2][8];
  #pragma unroll
  for (int nt = 0; nt < 8; nt++) {
    float bb = bs2[nt*16 + cl];
    accS[0][nt] = f32x4{bb, bb, bb, bb};
    accS[1][nt] = f32x4{bb, bb, bb, bb};
  }
  #pragma unroll
  for (int kt = 0; kt < 4; kt++) {
    short8 bf[8];
    #pragma unroll
    for (int nt = 0; nt < 8; nt++)
      bf[nt] = *reinterpret_cast<const short8*>(wp + 65536 + ((kt*8 + nt)*64 + lane)*8);
    #pragma unroll
    for (int rt = 0; rt < 2; rt++) {
      short8 af = *reinterpret_cast<const short8*>(T + (rt*16 + cl)*TS + kt*32 + kg*8);
      #pragma unroll
      for (int nt = 0; nt < 8; nt++)
        accS[rt][nt] = __builtin_amdgcn_mfma_f32_16x16x32_bf16(af, bf[nt], accS[rt][nt], 0, 0, 0);
    }
  }

  // ---- pe1: pin = [nprod(3) | radial(15) | pad] in-register ----
  #pragma unroll
  for (int nt = 0; nt < 8; nt++) {
    float bb = bp1[nt*16 + cl];
    acc[0][nt] = f32x4{bb, bb, bb, bb};
    acc[1][nt] = f32x4{bb, bb, bb, bb};
  }
  {
    short8 bf[8];
    #pragma unroll
    for (int nt = 0; nt < 8; nt++)
      bf[nt] = *reinterpret_cast<const short8*>(wp + 98304 + (nt*64 + lane)*8);
    #pragma unroll
    for (int rt = 0; rt < 2; rt++) {
      short8 af;
      if (kg == 0) {
        af[0]=(short)f2b(np[rt][0]); af[1]=(short)f2b(np[rt][1]); af[2]=(short)f2b(np[rt][2]);
        af[3]=(short)r0[rt][0]; af[4]=(short)r0[rt][1]; af[5]=(short)r0[rt][2];
        af[6]=(short)r0[rt][3]; af[7]=(short)r0[rt][4];
      } else if (kg == 1) {
        af[0]=(short)r0[rt][5]; af[1]=(short)r0[rt][6]; af[2]=(short)r0[rt][7];
        af[3]=(short)r1[rt][0]; af[4]=(short)r1[rt][1]; af[5]=(short)r1[rt][2];
        af[6]=(short)r1[rt][3]; af[7]=(short)r1[rt][4];
      } else if (kg == 2) {
        af[0]=(short)r1[rt][5]; af[1]=(short)r1[rt][6];
        af[2]=0; af[3]=0; af[4]=0; af[5]=0; af[6]=0; af[7]=0;
      } else {
        af[0]=0; af[1]=0; af[2]=0; af[3]=0; af[4]=0; af[5]=0; af[6]=0; af[7]=0;
      }
      #pragma unroll
      for (int nt = 0; nt < 8; nt++)
        acc[rt][nt] = __builtin_amdgcn_mfma_f32_16x16x32_bf16(af, bf[nt], acc[rt][nt], 0, 0, 0);
    }
  }
  #pragma unroll
  for (int rt = 0; rt < 2; rt++)
    #pragma unroll
    for (int nt = 0; nt < 8; nt++) {
      unsigned q0 = cvt_pk_bf16(silu_f(acc[rt][nt][0]), silu_f(acc[rt][nt][1]));
      unsigned q1 = cvt_pk_bf16(silu_f(acc[rt][nt][2]), silu_f(acc[rt][nt][3]));
      T[(rt*16 + kg*4 + 0)*TS + nt*16 + cl] = (unsigned short)(q0 & 0xffff);
      T[(rt*16 + kg*4 + 1)*TS + nt*16 + cl] = (unsigned short)(q0 >> 16);
      T[(rt*16 + kg*4 + 2)*TS + nt*16 + cl] = (unsigned short)(q1 & 0xffff);
      T[(rt*16 + kg*4 + 3)*TS + nt*16 + cl] = (unsigned short)(q1 >> 16);
    }

  // ---- pe2 in two N-halves; fold pos write + o=s2*pos + att partial ----
  float ps[2][4] = {{0,0,0,0},{0,0,0,0}};
  #pragma unroll
  for (int half = 0; half < 2; half++) {
    f32x4 ph[2][4];
    #pragma unroll
    for (int n4 = 0; n4 < 4; n4++) {
      float bb = bp2[(half*4 + n4)*16 + cl];
      ph[0][n4] = f32x4{bb, bb, bb, bb};
      ph[1][n4] = f32x4{bb, bb, bb, bb};
    }
    #pragma unroll
    for (int kt = 0; kt < 4; kt++) {
      short8 bf[4];
      #pragma unroll
      for (int n4 = 0; n4 < 4; n4++)
        bf[n4] = *reinterpret_cast<const short8*>(wp + 81920 + ((kt*8 + half*4 + n4)*64 + lane)*8);
      #pragma unroll
      for (int rt = 0; rt < 2; rt++) {
        short8 af = *reinterpret_cast<const short8*>(T + (rt*16 + cl)*TS + kt*32 + kg*8);
        #pragma unroll
        for (int n4 = 0; n4 < 4; n4++)
          ph[rt][n4] = __builtin_amdgcn_mfma_f32_16x16x32_bf16(af, bf[n4], ph[rt][n4], 0, 0, 0);
      }
    }
    #pragma unroll
    for (int rt = 0; rt < 2; rt++)
      #pragma unroll
      for (int n4 = 0; n4 < 4; n4++) {
        int nt = half*4 + n4;
        float wa = watt[nt*16 + cl];
        #pragma unroll
        for (int g = 0; g < 4; g++) {
          float p = ph[rt][n4][g];
          pos_o[(size_t)(e0 + rt*16 + kg*4 + g) * HID + nt*16 + cl] = p;
          float o = accS[rt][nt][g] * p;
          accS[rt][nt][g] = o;
          ps[rt][g] += o * wa;
        }
      }
  }

  // ---- attention + final out ----
  float ba = batt[0];
  #pragma unroll
  for (int rt = 0; rt < 2; rt++)
    #pragma unroll
    for (int g = 0; g < 4; g++) {
      float s = ps[rt][g];
      s += __shfl_xor(s, 1);
      s += __shfl_xor(s, 2);
      s += __shfl_xor(s, 4);
      s += __shfl_xor(s, 8);
      float av = fast_sigmoid(s + ba);
      #pragma unroll
      for (int nt = 0; nt < 8; nt++)
        out0[(size_t)(e0 + rt*16 + kg*4 + g) * HID + nt*16 + cl] = accS[rt][nt][g] * av;
    }
}

// ---------------- launcher ----------------------------------------------------
extern "C" void kernel_launch(void* const* d_in, const int* in_sizes, int n_in,
                              void* d_out, int out_size, void* d_ws, size_t ws_size,
                              hipStream_t stream) {
  (void)in_sizes; (void)n_in; (void)out_size; (void)ws_size;
  const float* h     = (const float*)d_in[0];
  const float* coord = (const float*)d_in[1];
  const int*   edges = (const int*)d_in[2];
  const float* W_ce1 = (const float*)d_in[3];  const float* b_ce1 = (const float*)d_in[4];
  const float* W_ce2 = (const float*)d_in[5];  const float* b_ce2 = (const float*)d_in[6];
  const float* W_pe1 = (const float*)d_in[7];  const float* b_pe1 = (const float*)d_in[8];
  const float* W_pe2 = (const float*)d_in[9];  const float* b_pe2 = (const float*)d_in[10];
  const float* W_s1  = (const float*)d_in[11]; const float* b_s1  = (const float*)d_in[12];
  const float* W_s2  = (const float*)d_in[13]; const float* b_s2  = (const float*)d_in[14];
  const float* W_att = (const float*)d_in[15]; const float* b_att = (const float*)d_in[16];

  float* out  = (float*)d_out;
  float* chem = out  + (size_t)E_EDGES * HID;
  float* pos  = chem + (size_t)E_EDGES * HID;
  float* cdn  = pos  + (size_t)E_EDGES * HID;

  char* ws = (char*)d_ws;
  float* nf             = (float*)(ws);                      // NN*12 f32   (960,000 B)
  unsigned short* Htb   = (unsigned short*)(ws + 960000);    // NN*128 bf16 (5,120,000 B)
  unsigned short* Hbb   = (unsigned short*)(ws + 6080000);   // NN*128 bf16 (5,120,000 B)
  unsigned short* wpack = (unsigned short*)(ws + 11200000);  // 102400 bf16 (204,800 B)
  unsigned short* rad16 = (unsigned short*)(ws + 11404800);  // E*16 bf16   (10,240,000 B)

  prepack_k<<<635, 256, 0, stream>>>(W_ce1, W_ce2, W_s1, W_s2, W_pe2, W_pe1, wpack, nf);
  geomnode_k<<<1875, 256, 0, stream>>>(edges, edges + E_EDGES, coord, h, wpack, b_ce1,
                                       nf, rad16, cdn, Htb, Hbb);
  edge_mlp_k<<<E_EDGES / 256, 512, 0, stream>>>(edges, edges + E_EDGES, Htb, Hbb,
                                                rad16, nf, wpack,
                                                b_ce2, b_s1, b_s2, b_pe1, b_pe2,
                                                W_att, b_att, out, chem, pos);
}

// Round 19
// 309.734 us; speedup vs baseline: 1.0721x; 1.0721x over previous
//
#include <hip/hip_runtime.h>

#define E_EDGES 320000
#define NN 20000
#define HID 128
#define TS 136   // LDS T-tile stride (bf16 elems): 272B == 16 mod 128 -> spread banks

typedef __attribute__((ext_vector_type(8))) short short8;
typedef __attribute__((ext_vector_type(4))) float f32x4;
typedef __attribute__((ext_vector_type(8))) unsigned short us8;
typedef __attribute__((ext_vector_type(4))) unsigned uint4v;

__device__ __forceinline__ unsigned short f2b(float f) {
  unsigned u = __builtin_bit_cast(unsigned, f);
  u += 0x7fffu + ((u >> 16) & 1u);
  return (unsigned short)(u >> 16);
}
__device__ __forceinline__ unsigned cvt_pk_bf16(float lo, float hi) {
  unsigned r;
  asm("v_cvt_pk_bf16_f32 %0, %1, %2" : "=v"(r) : "v"(lo), "v"(hi));
  return r;
}
#define LOG2E 1.44269504f
__device__ __forceinline__ float fast_sigmoid(float x) {
  return __builtin_amdgcn_rcpf(1.0f + __builtin_amdgcn_exp2f(-x * LOG2E));
}
__device__ __forceinline__ float silu_f(float x) { return x * fast_sigmoid(x); }

// ---------------- K1: weight prepack + zero nf (stride-12) -------------------
__global__ void prepack_k(const float* __restrict__ Wce1, const float* __restrict__ Wce2,
                          const float* __restrict__ Ws1,  const float* __restrict__ Ws2,
                          const float* __restrict__ Wpe2, const float* __restrict__ Wpe1,
                          unsigned short* __restrict__ dst, float* __restrict__ nf) {
  int b = blockIdx.x;
  if (b >= 400) {
    int j = (b - 400) * 256 + threadIdx.x;
    if (j < NN * 12 / 4)
      reinterpret_cast<float4*>(nf)[j] = float4{0.0f, 0.0f, 0.0f, 0.0f};
    return;
  }
  int i = b * 256 + threadIdx.x;
  const float* W; int Ksrc, base;
  if (i < 32768)      { W = Wce1; Ksrc = 256; base = 0; }
  else if (i < 49152) { W = Wce2; Ksrc = 128; base = 32768; }
  else if (i < 65536) { W = Ws1;  Ksrc = 128; base = 49152; }
  else if (i < 81920) { W = Ws2;  Ksrc = 128; base = 65536; }
  else if (i < 98304) { W = Wpe2; Ksrc = 128; base = 81920; }
  else                { W = Wpe1; Ksrc = 18;  base = 98304; }
  int j = i - base;
  int r = j & 7, lane = (j >> 3) & 63, ntg = (j >> 9) & 7, kt = j >> 12;
  int sk = kt * 32 + ((lane >> 4) << 3) + r;
  int sn = (ntg << 4) + (lane & 15);
  float v = (sk < Ksrc) ? W[sk * HID + sn] : 0.0f;
  dst[i] = f2b(v);
}

// ---------------- K2: edge geometry (blocks 0..1249) + node ce1 (1250..1874) --
__global__ __launch_bounds__(256) void geomnode_k(
    const int* __restrict__ erow, const int* __restrict__ ecol,
    const float* __restrict__ coord, const float* __restrict__ h,
    const unsigned short* __restrict__ wp, const float* __restrict__ b1,
    float* __restrict__ nf, unsigned short* __restrict__ rad16,
    float* __restrict__ cdn,
    unsigned short* __restrict__ Htb, unsigned short* __restrict__ Hbb) {
  int b = blockIdx.x;
  if (b < 1250) {
    int i = b * 256 + threadIdx.x;
    int r = erow[i], c = ecol[i];
    float dx = coord[r*3+0] - coord[c*3+0];
    float dy = coord[r*3+1] - coord[c*3+1];
    float dz = coord[r*3+2] - coord[c*3+2];
    float r2 = dx*dx + dy*dy + dz*dz;
    float dn = sqrtf(r2);
    float invn = __builtin_amdgcn_rcpf(dn + 1e-8f);
    cdn[i*3+0] = dx*invn; cdn[i*3+1] = dy*invn; cdn[i*3+2] = dz*invn;

    unsigned short rv[16];
    float t = 1.0f;
    #pragma unroll
    for (int s = 0; s < 15; s++) {
      rv[s] = f2b(__builtin_amdgcn_exp2f(r2 * (-0.5f * LOG2E) / t));
      t *= 2.25f;
    }
    rv[15] = 0;
    us8 lo, hi;
    #pragma unroll
    for (int k = 0; k < 8; k++) { lo[k] = rv[k]; hi[k] = rv[8+k]; }
    *reinterpret_cast<us8*>(rad16 + (size_t)i*16)     = lo;
    *reinterpret_cast<us8*>(rad16 + (size_t)i*16 + 8) = hi;

    float inv = __builtin_amdgcn_rcpf(dn);
    float w3 = inv*inv*inv, w4 = w3*inv, w5 = w4*inv;
    float* p = nf + r*12;
    unsafeAtomicAdd(p+0, w3*dx); unsafeAtomicAdd(p+1, w3*dy); unsafeAtomicAdd(p+2, w3*dz);
    unsafeAtomicAdd(p+3, w4*dx); unsafeAtomicAdd(p+4, w4*dy); unsafeAtomicAdd(p+5, w4*dz);
    unsafeAtomicAdd(p+6, w5*dx); unsafeAtomicAdd(p+7, w5*dy); unsafeAtomicAdd(p+8, w5*dz);
    return;
  }
  const int tid = threadIdx.x, lane = tid & 63, wv = tid >> 6;
  const int cl = lane & 15, kg = lane >> 4;
  const int w = (b - 1250) * 4 + wv;   // 0..2499
  const int half = w & 1;
  const int n0 = (w >> 1) * 16;

  f32x4 acc[8];
  #pragma unroll
  for (int nt = 0; nt < 8; nt++) {
    float bb = half ? 0.0f : b1[nt*16 + cl];
    acc[nt] = f32x4{bb, bb, bb, bb};
  }
  #pragma unroll
  for (int k4 = 0; k4 < 4; k4++) {
    int kt = half*4 + k4;
    const float* hp = h + (size_t)(n0 + cl) * HID + k4*32 + kg*8;
    float4 v0 = *reinterpret_cast<const float4*>(hp);
    float4 v1 = *reinterpret_cast<const float4*>(hp + 4);
    unsigned p0 = cvt_pk_bf16(v0.x, v0.y), p1 = cvt_pk_bf16(v0.z, v0.w);
    unsigned p2 = cvt_pk_bf16(v1.x, v1.y), p3 = cvt_pk_bf16(v1.z, v1.w);
    short8 af = __builtin_bit_cast(short8, uint4v{p0, p1, p2, p3});
    #pragma unroll
    for (int nt = 0; nt < 8; nt++) {
      short8 bf = *reinterpret_cast<const short8*>(wp + ((kt*8 + nt)*64 + lane)*8);
      acc[nt] = __builtin_amdgcn_mfma_f32_16x16x32_bf16(af, bf, acc[nt], 0, 0, 0);
    }
  }
  unsigned short* dst = half ? Hbb : Htb;
  #pragma unroll
  for (int nt = 0; nt < 8; nt++) {
    unsigned q0 = cvt_pk_bf16(acc[nt][0], acc[nt][1]);
    unsigned q1 = cvt_pk_bf16(acc[nt][2], acc[nt][3]);
    dst[(size_t)(n0 + kg*4 + 0) * HID + nt*16 + cl] = (unsigned short)(q0 & 0xffff);
    dst[(size_t)(n0 + kg*4 + 1) * HID + nt*16 + cl] = (unsigned short)(q0 >> 16);
    dst[(size_t)(n0 + kg*4 + 2) * HID + nt*16 + cl] = (unsigned short)(q1 & 0xffff);
    dst[(size_t)(n0 + kg*4 + 3) * HID + nt*16 + cl] = (unsigned short)(q1 >> 16);
  }
}

// ---------------- K3: edge kernel v6 — 32 edges/wave (session best, R17) ------
__global__ __launch_bounds__(256, 2) void edge_mlp_k(
    const int* __restrict__ erow, const int* __restrict__ ecol,
    const unsigned short* __restrict__ Htb, const unsigned short* __restrict__ Hbb,
    const unsigned short* __restrict__ rad16, const float* __restrict__ nf,
    const unsigned short* __restrict__ wp,
    const float* __restrict__ b2,  const float* __restrict__ bs1,
    const float* __restrict__ bs2, const float* __restrict__ bp1,
    const float* __restrict__ bp2,
    const float* __restrict__ watt, const float* __restrict__ batt,
    float* __restrict__ out0, float* __restrict__ chem_o, float* __restrict__ pos_o) {
  __shared__ unsigned short sT[4][32 * TS];
  const int tid = threadIdx.x, lane = tid & 63, wv = tid >> 6;
  const int cl = lane & 15, kg = lane >> 4;
  const int e0 = (blockIdx.x * 4 + wv) * 32;
  unsigned short* T = sT[wv];

  int er_[2], ec_[2];
  er_[0] = erow[e0 + cl];      ec_[0] = ecol[e0 + cl];
  er_[1] = erow[e0 + 16 + cl]; ec_[1] = ecol[e0 + 16 + cl];

  // early-issue long-latency side loads (hide under ce2/s1/s2 chain)
  us8 r0[2], r1[2];
  #pragma unroll
  for (int rt = 0; rt < 2; rt++) {
    r0[rt] = *reinterpret_cast<const us8*>(rad16 + (size_t)(e0 + rt*16 + cl)*16);
    r1[rt] = *reinterpret_cast<const us8*>(rad16 + (size_t)(e0 + rt*16 + cl)*16 + 8);
  }
  float np[2][3];
  if (kg == 0) {
    #pragma unroll
    for (int rt = 0; rt < 2; rt++) {
      const float4* ap = reinterpret_cast<const float4*>(nf + er_[rt]*12);
      const float4* bp = reinterpret_cast<const float4*>(nf + ec_[rt]*12);
      float4 A0 = ap[0], A1 = ap[1], A2 = ap[2];
      float4 B0 = bp[0], B1 = bp[1], B2 = bp[2];
      {
        float d  = A0.x*B0.x + A0.y*B0.y + A0.z*B0.z;
        float na = A0.x*A0.x + A0.y*A0.y + A0.z*A0.z;
        float nb = B0.x*B0.x + B0.y*B0.y + B0.z*B0.z;
        np[rt][0] = d * __builtin_amdgcn_rcpf(sqrtf(na) + 1e-8f)
                      * __builtin_amdgcn_rcpf(sqrtf(nb) + 1e-8f);
      }
      {
        float d  = A0.w*B0.w + A1.x*B1.x + A1.y*B1.y;
        float na = A0.w*A0.w + A1.x*A1.x + A1.y*A1.y;
        float nb = B0.w*B0.w + B1.x*B1.x + B1.y*B1.y;
        np[rt][1] = d * __builtin_amdgcn_rcpf(sqrtf(na) + 1e-8f)
                      * __builtin_amdgcn_rcpf(sqrtf(nb) + 1e-8f);
      }
      {
        float d  = A1.z*B1.z + A1.w*B1.w + A2.x*B2.x;
        float na = A1.z*A1.z + A1.w*A1.w + A2.x*A2.x;
        float nb = B1.z*B1.z + B1.w*B1.w + B2.x*B2.x;
        np[rt][2] = d * __builtin_amdgcn_rcpf(sqrtf(na) + 1e-8f)
                      * __builtin_amdgcn_rcpf(sqrtf(nb) + 1e-8f);
      }
    }
  }

  // ---- ce2: A = silu(Htop[row] + Hbot[col]) from bf16 tables ----
  f32x4 acc[2][8];
  #pragma unroll
  for (int nt = 0; nt < 8; nt++) {
    float bb = b2[nt*16 + cl];
    acc[0][nt] = f32x4{bb, bb, bb, bb};
    acc[1][nt] = f32x4{bb, bb, bb, bb};
  }
  #pragma unroll
  for (int kt = 0; kt < 4; kt++) {
    short8 bf[8];
    #pragma unroll
    for (int nt = 0; nt < 8; nt++)
      bf[nt] = *reinterpret_cast<const short8*>(wp + 32768 + ((kt*8 + nt)*64 + lane)*8);
    #pragma unroll
    for (int rt = 0; rt < 2; rt++) {
      uint4v ta = *reinterpret_cast<const uint4v*>(Htb + (size_t)er_[rt] * HID + kt*32 + kg*8);
      uint4v tb = *reinterpret_cast<const uint4v*>(Hbb + (size_t)ec_[rt] * HID + kt*32 + kg*8);
      unsigned pw[4];
      #pragma unroll
      for (int p = 0; p < 4; p++) {
        float alo = __builtin_bit_cast(float, ta[p] << 16);
        float ahi = __builtin_bit_cast(float, ta[p] & 0xffff0000u);
        float blo = __builtin_bit_cast(float, tb[p] << 16);
        float bhi = __builtin_bit_cast(float, tb[p] & 0xffff0000u);
        pw[p] = cvt_pk_bf16(silu_f(alo + blo), silu_f(ahi + bhi));
      }
      short8 af = __builtin_bit_cast(short8, uint4v{pw[0], pw[1], pw[2], pw[3]});
      #pragma unroll
      for (int nt = 0; nt < 8; nt++)
        acc[rt][nt] = __builtin_amdgcn_mfma_f32_16x16x32_bf16(af, bf[nt], acc[rt][nt], 0, 0, 0);
    }
  }
  #pragma unroll
  for (int rt = 0; rt < 2; rt++)
    #pragma unroll
    for (int nt = 0; nt < 8; nt++) {
      #pragma unroll
      for (int g = 0; g < 4; g++)
        chem_o[(size_t)(e0 + rt*16 + kg*4 + g) * HID + nt*16 + cl] = acc[rt][nt][g];
      unsigned q0 = cvt_pk_bf16(acc[rt][nt][0], acc[rt][nt][1]);
      unsigned q1 = cvt_pk_bf16(acc[rt][nt][2], acc[rt][nt][3]);
      T[(rt*16 + kg*4 + 0)*TS + nt*16 + cl] = (unsigned short)(q0 & 0xffff);
      T[(rt*16 + kg*4 + 1)*TS + nt*16 + cl] = (unsigned short)(q0 >> 16);
      T[(rt*16 + kg*4 + 2)*TS + nt*16 + cl] = (unsigned short)(q1 & 0xffff);
      T[(rt*16 + kg*4 + 3)*TS + nt*16 + cl] = (unsigned short)(q1 >> 16);
    }

  // ---- s1: silu(T @ Ws1 + bs1) -> T ----
  #pragma unroll
  for (int nt = 0; nt < 8; nt++) {
    float bb = bs1[nt*16 + cl];
    acc[0][nt] = f32x4{bb, bb, bb, bb};
    acc[1][nt] = f32x4{bb, bb, bb, bb};
  }
  #pragma unroll
  for (int kt = 0; kt < 4; kt++) {
    short8 bf[8];
    #pragma unroll
    for (int nt = 0; nt < 8; nt++)
      bf[nt] = *reinterpret_cast<const short8*>(wp + 49152 + ((kt*8 + nt)*64 + lane)*8);
    #pragma unroll
    for (int rt = 0; rt < 2; rt++) {
      short8 af = *reinterpret_cast<const short8*>(T + (rt*16 + cl)*TS + kt*32 + kg*8);
      #pragma unroll
      for (int nt = 0; nt < 8; nt++)
        acc[rt][nt] = __builtin_amdgcn_mfma_f32_16x16x32_bf16(af, bf[nt], acc[rt][nt], 0, 0, 0);
    }
  }
  #pragma unroll
  for (int rt = 0; rt < 2; rt++)
    #pragma unroll
    for (int nt = 0; nt < 8; nt++) {
      unsigned q0 = cvt_pk_bf16(silu_f(acc[rt][nt][0]), silu_f(acc[rt][nt][1]));
      unsigned q1 = cvt_pk_bf16(silu_f(acc[rt][nt][2]), silu_f(acc[rt][nt][3]));
      T[(rt*16 + kg*4 + 0)*TS + nt*16 + cl] = (unsigned short)(q0 & 0xffff);
      T[(rt*16 + kg*4 + 1)*TS + nt*16 + cl] = (unsigned short)(q0 >> 16);
      T[(rt*16 + kg*4 + 2)*TS + nt*16 + cl] = (unsigned short)(q1 & 0xffff);
      T[(rt*16 + kg*4 + 3)*TS + nt*16 + cl] = (unsigned short)(q1 >> 16);
    }

  // ---- s2 -> accS (held) ----
  f32x4 accS[2][8];
  #pragma unroll
  for (int nt = 0; nt < 8; nt++) {
    float bb = bs2[nt*16 + cl];
    accS[0][nt] = f32x4{bb, bb, bb, bb};
    accS[1][nt] = f32x4{bb, bb, bb, bb};
  }
  #pragma unroll
  for (int kt = 0; kt < 4; kt++) {
    short8 bf[8];
    #pragma unroll
    for (int nt = 0; nt < 8; nt++)
      bf[nt] = *reinterpret_cast<const short8*>(wp + 65536 + ((kt*8 + nt)*64 + lane)*8);
    #pragma unroll
    for (int rt = 0; rt < 2; rt++) {
      short8 af = *reinterpret_cast<const short8*>(T + (rt*16 + cl)*TS + kt*32 + kg*8);
      #pragma unroll
      for (int nt = 0; nt < 8; nt++)
        accS[rt][nt] = __builtin_amdgcn_mfma_f32_16x16x32_bf16(af, bf[nt], accS[rt][nt], 0, 0, 0);
    }
  }

  // ---- pe1: pin = [nprod(3) | radial(15) | pad] in-register ----
  #pragma unroll
  for (int nt = 0; nt < 8; nt++) {
    float bb = bp1[nt*16 + cl];
    acc[0][nt] = f32x4{bb, bb, bb, bb};
    acc[1][nt] = f32x4{bb, bb, bb, bb};
  }
  {
    short8 bf[8];
    #pragma unroll
    for (int nt = 0; nt < 8; nt++)
      bf[nt] = *reinterpret_cast<const short8*>(wp + 98304 + (nt*64 + lane)*8);
    #pragma unroll
    for (int rt = 0; rt < 2; rt++) {
      short8 af;
      if (kg == 0) {
        af[0]=(short)f2b(np[rt][0]); af[1]=(short)f2b(np[rt][1]); af[2]=(short)f2b(np[rt][2]);
        af[3]=(short)r0[rt][0]; af[4]=(short)r0[rt][1]; af[5]=(short)r0[rt][2];
        af[6]=(short)r0[rt][3]; af[7]=(short)r0[rt][4];
      } else if (kg == 1) {
        af[0]=(short)r0[rt][5]; af[1]=(short)r0[rt][6]; af[2]=(short)r0[rt][7];
        af[3]=(short)r1[rt][0]; af[4]=(short)r1[rt][1]; af[5]=(short)r1[rt][2];
        af[6]=(short)r1[rt][3]; af[7]=(short)r1[rt][4];
      } else if (kg == 2) {
        af[0]=(short)r1[rt][5]; af[1]=(short)r1[rt][6];
        af[2]=0; af[3]=0; af[4]=0; af[5]=0; af[6]=0; af[7]=0;
      } else {
        af[0]=0; af[1]=0; af[2]=0; af[3]=0; af[4]=0; af[5]=0; af[6]=0; af[7]=0;
      }
      #pragma unroll
      for (int nt = 0; nt < 8; nt++)
        acc[rt][nt] = __builtin_amdgcn_mfma_f32_16x16x32_bf16(af, bf[nt], acc[rt][nt], 0, 0, 0);
    }
  }
  #pragma unroll
  for (int rt = 0; rt < 2; rt++)
    #pragma unroll
    for (int nt = 0; nt < 8; nt++) {
      unsigned q0 = cvt_pk_bf16(silu_f(acc[rt][nt][0]), silu_f(acc[rt][nt][1]));
      unsigned q1 = cvt_pk_bf16(silu_f(acc[rt][nt][2]), silu_f(acc[rt][nt][3]));
      T[(rt*16 + kg*4 + 0)*TS + nt*16 + cl] = (unsigned short)(q0 & 0xffff);
      T[(rt*16 + kg*4 + 1)*TS + nt*16 + cl] = (unsigned short)(q0 >> 16);
      T[(rt*16 + kg*4 + 2)*TS + nt*16 + cl] = (unsigned short)(q1 & 0xffff);
      T[(rt*16 + kg*4 + 3)*TS + nt*16 + cl] = (unsigned short)(q1 >> 16);
    }

  // ---- pe2 in two N-halves; fold pos write + o=s2*pos + att partial ----
  float ps[2][4] = {{0,0,0,0},{0,0,0,0}};
  #pragma unroll
  for (int half = 0; half < 2; half++) {
    f32x4 ph[2][4];
    #pragma unroll
    for (int n4 = 0; n4 < 4; n4++) {
      float bb = bp2[(half*4 + n4)*16 + cl];
      ph[0][n4] = f32x4{bb, bb, bb, bb};
      ph[1][n4] = f32x4{bb, bb, bb, bb};
    }
    #pragma unroll
    for (int kt = 0; kt < 4; kt++) {
      short8 bf[4];
      #pragma unroll
      for (int n4 = 0; n4 < 4; n4++)
        bf[n4] = *reinterpret_cast<const short8*>(wp + 81920 + ((kt*8 + half*4 + n4)*64 + lane)*8);
      #pragma unroll
      for (int rt = 0; rt < 2; rt++) {
        short8 af = *reinterpret_cast<const short8*>(T + (rt*16 + cl)*TS + kt*32 + kg*8);
        #pragma unroll
        for (int n4 = 0; n4 < 4; n4++)
          ph[rt][n4] = __builtin_amdgcn_mfma_f32_16x16x32_bf16(af, bf[n4], ph[rt][n4], 0, 0, 0);
      }
    }
    #pragma unroll
    for (int rt = 0; rt < 2; rt++)
      #pragma unroll
      for (int n4 = 0; n4 < 4; n4++) {
        int nt = half*4 + n4;
        float wa = watt[nt*16 + cl];
        #pragma unroll
        for (int g = 0; g < 4; g++) {
          float p = ph[rt][n4][g];
          pos_o[(size_t)(e0 + rt*16 + kg*4 + g) * HID + nt*16 + cl] = p;
          float o = accS[rt][nt][g] * p;
          accS[rt][nt][g] = o;
          ps[rt][g] += o * wa;
        }
      }
  }

  // ---- attention + final out ----
  float ba = batt[0];
  #pragma unroll
  for (int rt = 0; rt < 2; rt++)
    #pragma unroll
    for (int g = 0; g < 4; g++) {
      float s = ps[rt][g];
      s += __shfl_xor(s, 1);
      s += __shfl_xor(s, 2);
      s += __shfl_xor(s, 4);
      s += __shfl_xor(s, 8);
      float av = fast_sigmoid(s + ba);
      #pragma unroll
      for (int nt = 0; nt < 8; nt++)
        out0[(size_t)(e0 + rt*16 + kg*4 + g) * HID + nt*16 + cl] = accS[rt][nt][g] * av;
    }
}

// ---------------- launcher ----------------------------------------------------
extern "C" void kernel_launch(void* const* d_in, const int* in_sizes, int n_in,
                              void* d_out, int out_size, void* d_ws, size_t ws_size,
                              hipStream_t stream) {
  (void)in_sizes; (void)n_in; (void)out_size; (void)ws_size;
  const float* h     = (const float*)d_in[0];
  const float* coord = (const float*)d_in[1];
  const int*   edges = (const int*)d_in[2];
  const float* W_ce1 = (const float*)d_in[3];  const float* b_ce1 = (const float*)d_in[4];
  const float* W_ce2 = (const float*)d_in[5];  const float* b_ce2 = (const float*)d_in[6];
  const float* W_pe1 = (const float*)d_in[7];  const float* b_pe1 = (const float*)d_in[8];
  const float* W_pe2 = (const float*)d_in[9];  const float* b_pe2 = (const float*)d_in[10];
  const float* W_s1  = (const float*)d_in[11]; const float* b_s1  = (const float*)d_in[12];
  const float* W_s2  = (const float*)d_in[13]; const float* b_s2  = (const float*)d_in[14];
  const float* W_att = (const float*)d_in[15]; const float* b_att = (const float*)d_in[16];

  float* out  = (float*)d_out;
  float* chem = out  + (size_t)E_EDGES * HID;
  float* pos  = chem + (size_t)E_EDGES * HID;
  float* cdn  = pos  + (size_t)E_EDGES * HID;

  char* ws = (char*)d_ws;
  float* nf             = (float*)(ws);                      // NN*12 f32   (960,000 B)
  unsigned short* Htb   = (unsigned short*)(ws + 960000);    // NN*128 bf16 (5,120,000 B)
  unsigned short* Hbb   = (unsigned short*)(ws + 6080000);   // NN*128 bf16 (5,120,000 B)
  unsigned short* wpack = (unsigned short*)(ws + 11200000);  // 102400 bf16 (204,800 B)
  unsigned short* rad16 = (unsigned short*)(ws + 11404800);  // E*16 bf16   (10,240,000 B)

  prepack_k<<<635, 256, 0, stream>>>(W_ce1, W_ce2, W_s1, W_s2, W_pe2, W_pe1, wpack, nf);
  geomnode_k<<<1875, 256, 0, stream>>>(edges, edges + E_EDGES, coord, h, wpack, b_ce1,
                                       nf, rad16, cdn, Htb, Hbb);
  edge_mlp_k<<<E_EDGES / 128, 256, 0, stream>>>(edges, edges + E_EDGES, Htb, Hbb,
                                                rad16, nf, wpack,
                                                b_ce2, b_s1, b_s2, b_pe1, b_pe2,
                                                W_att, b_att, out, chem, pos);
}